// Round 3
// baseline (47.814 us; speedup 1.0000x reference)
//
#include <hip/hip_runtime.h>

// YOLO loss: predictions (N,7,7,30) f32, target (N,7,7,25) f32 -> scalar f32.
// S=7, B=2, C=20. Memory-bound reduction (~176 MB -> 1 float).
//
// Round 3:
//  - Linear LDS staging (no transpose): coalesced float2 copy, zero write
//    bank conflicts, zero address math. Compute reads: pred stride 30 words
//    (4-way conflict, ~1.58x, hidden), tgt stride 25 (coprime w/ 32: free).
//  - Persistent 512 blocks (2/CU), each owns 1568 contiguous cells =
//    6 full 256-cell tiles + 32-cell remainder; register prefetch of tile
//    f+1 issued before compute of tile f keeps the memory queue full.
//  - Fused final reduction via last-block-done atomic counter (no 2nd kernel).

#define S7 7
#define CELL_P 30
#define CELL_T 25
#define TPB 256
#define NBLK 512

__device__ __forceinline__ void load_tile(const float2* __restrict__ p2,
                                          const float2* __restrict__ t2,
                                          int base_p, int base_t,
                                          int lim_p, int lim_t, int t,
                                          float2* rp, float2* rt)
{
    #pragma unroll
    for (int i = 0; i < 15; ++i) {
        int idx = t + TPB * i;
        if (idx < lim_p) rp[i] = p2[base_p + idx];
    }
    #pragma unroll
    for (int i = 0; i < 13; ++i) {
        int idx = t + TPB * i;
        if (idx < lim_t) rt[i] = t2[base_t + idx];
    }
}

__device__ __forceinline__ void store_tile(float2* sp2, float2* st2,
                                           int lim_p, int lim_t, int t,
                                           const float2* rp, const float2* rt)
{
    #pragma unroll
    for (int i = 0; i < 15; ++i) {
        int idx = t + TPB * i;
        if (idx < lim_p) sp2[idx] = rp[i];
    }
    #pragma unroll
    for (int i = 0; i < 13; ++i) {
        int idx = t + TPB * i;
        if (idx < lim_t) st2[idx] = rt[i];
    }
}

__device__ __forceinline__ float cell_loss(const float* __restrict__ pv,
                                           const float* __restrict__ tv,
                                           int cell)
{
    int rem  = cell % 49;
    float gx = (float)(rem % S7);   // column (axis 2)
    float gy = (float)(rem / S7);   // row    (axis 1)

    float obj = (tv[4] > 0.5f) ? 1.0f : 0.0f;

    float gcx = (gx + tv[0]) * 64.0f;
    float gcy = (gy + tv[1]) * 64.0f;
    float gw  = tv[2] * 448.0f;
    float gh  = tv[3] * 448.0f;
    float gx1 = gcx - gw * 0.5f, gy1 = gcy - gh * 0.5f;
    float gx2 = gcx + gw * 0.5f, gy2 = gcy + gh * 0.5f;
    float ga  = gw * gh;

    float iou[2], dxy[2], dwh[2], conf[2];
    #pragma unroll
    for (int b = 0; b < 2; ++b) {
        float b0 = pv[b * 5 + 0], b1 = pv[b * 5 + 1], b2 = pv[b * 5 + 2];
        float b3 = pv[b * 5 + 3], b4 = pv[b * 5 + 4];
        float pcx = (gx + b0) * 64.0f;
        float pcy = (gy + b1) * 64.0f;
        float pw  = b2 * 448.0f;
        float ph  = b3 * 448.0f;
        float px1 = pcx - pw * 0.5f, py1 = pcy - ph * 0.5f;
        float px2 = pcx + pw * 0.5f, py2 = pcy + ph * 0.5f;
        float pa  = pw * ph;

        float iw = fmaxf(fminf(px2, gx2) - fmaxf(px1, gx1), 0.0f);
        float ih = fmaxf(fminf(py2, gy2) - fmaxf(py1, gy1), 0.0f);
        float inter = iw * ih;
        iou[b] = inter / (pa + ga - inter + 1e-6f);

        float dx = b0 - tv[0], dy = b1 - tv[1];
        dxy[b] = dx * dx + dy * dy;
        float sw = sqrtf(fmaxf(b2, 0.0f)) - sqrtf(fmaxf(tv[2], 0.0f));
        float sh = sqrtf(fmaxf(b3, 0.0f)) - sqrtf(fmaxf(tv[3], 0.0f));
        dwh[b] = sw * sw + sh * sh;
        conf[b] = b4;
    }

    int best = (iou[1] > iou[0]) ? 1 : 0;   // argmax ties -> first (box 0)

    float loss = 0.0f;
    #pragma unroll
    for (int b = 0; b < 2; ++b) {
        float resp_obj = (b == best) ? obj : 0.0f;
        loss += 5.0f * resp_obj * (dxy[b] + dwh[b]);          // coord
        float d = conf[b] - iou[b];
        loss += resp_obj * d * d;                              // conf obj
        loss += 0.5f * (1.0f - resp_obj) * conf[b] * conf[b];  // conf noobj
    }

    float cls = 0.0f;
    #pragma unroll
    for (int c = 0; c < 20; ++c) {
        float d = pv[10 + c] - tv[5 + c];
        cls += d * d;
    }
    return loss + obj * cls;
}

__global__ __launch_bounds__(TPB) void yolo_fused_kernel(
    const float* __restrict__ pred, const float* __restrict__ tgt,
    float* __restrict__ partial, unsigned int* __restrict__ cnt,
    float* __restrict__ out, int cpb, float invN)
{
    __shared__ float sp[TPB * CELL_P];   // 30720 B, linear (global layout)
    __shared__ float st[TPB * CELL_T];   // 25600 B
    __shared__ float sred[4];
    __shared__ bool  sdone;

    const int t   = threadIdx.x;
    const int bid = blockIdx.x;
    if (t == 0) sdone = false;

    const long long cell0 = (long long)bid * cpb;
    const int fullTiles = cpb >> 8;          // 6
    const int rem       = cpb & 255;         // 32
    const int tiles     = fullTiles + (rem ? 1 : 0);

    const float2* p2 = reinterpret_cast<const float2*>(pred + cell0 * CELL_P);
    const float2* t2 = reinterpret_cast<const float2*>(tgt  + cell0 * CELL_T);
    float2* sp2 = reinterpret_cast<float2*>(sp);
    float2* st2 = reinterpret_cast<float2*>(st);

    float2 rp[15], rt[13];
    float  acc = 0.0f;

    // prefetch tile 0
    {
        int lp = (0 < fullTiles) ? TPB * 15 : rem * 15;
        int lt = (0 < fullTiles) ? (TPB * 25) / 2 : (rem * 25) / 2;
        load_tile(p2, t2, 0, 0, lp, lt, t, rp, rt);
    }

    for (int f = 0; f < tiles; ++f) {
        const bool full = (f < fullTiles);
        const int  nc   = full ? TPB : rem;
        const int  lp   = nc * 15;          // float2 count (pred)
        const int  lt   = (nc * 25) >> 1;   // float2 count (tgt), 25*nc even

        __syncthreads();                    // LDS free to overwrite
        store_tile(sp2, st2, lp, lt, t, rp, rt);

        if (f + 1 < tiles) {                // prefetch next tile
            const bool nfull = (f + 1 < fullTiles);
            const int  nnc   = nfull ? TPB : rem;
            load_tile(p2, t2, (f + 1) * TPB * 15, (f + 1) * (TPB * 25 / 2),
                      nnc * 15, (nnc * 25) >> 1, t, rp, rt);
        }
        __syncthreads();

        if (t < nc)
            acc += cell_loss(sp + t * CELL_P, st + t * CELL_T,
                             (int)(cell0 + f * TPB + t));
    }

    // ---- block reduce ----
    #pragma unroll
    for (int off = 32; off > 0; off >>= 1)
        acc += __shfl_down(acc, off, 64);

    int lane = t & 63;
    int wid  = t >> 6;
    if (lane == 0) sred[wid] = acc;
    __syncthreads();
    if (t == 0) {
        partial[bid] = sred[0] + sred[1] + sred[2] + sred[3];
        __threadfence();
        unsigned int old = atomicAdd(cnt, 1u);
        sdone = (old == (unsigned int)(gridDim.x - 1));
    }
    __syncthreads();

    // ---- last block: deterministic fixed-order final sum ----
    if (sdone) {
        __threadfence();
        float s = 0.0f;
        for (int i = t; i < (int)gridDim.x; i += TPB)
            s += partial[i];
        #pragma unroll
        for (int off = 32; off > 0; off >>= 1)
            s += __shfl_down(s, off, 64);
        __syncthreads();
        if (lane == 0) sred[wid] = s;
        __syncthreads();
        if (t == 0)
            out[0] = (sred[0] + sred[1] + sred[2] + sred[3]) * invN;
    }
}

extern "C" void kernel_launch(void* const* d_in, const int* in_sizes, int n_in,
                              void* d_out, int out_size, void* d_ws, size_t ws_size,
                              hipStream_t stream)
{
    const float* pred = (const float*)d_in[0];
    const float* tgt  = (const float*)d_in[1];
    float* out        = (float*)d_out;
    float* partial    = (float*)d_ws;                       // NBLK floats
    unsigned int* cnt = (unsigned int*)((char*)d_ws + NBLK * sizeof(float));

    int ncells = in_sizes[0] / CELL_P;      // N*S*S = 802816
    int N      = ncells / 49;
    int cpb    = ncells / NBLK;             // 1568 = 6*256 + 32

    hipMemsetAsync(cnt, 0, sizeof(unsigned int), stream);
    yolo_fused_kernel<<<NBLK, TPB, 0, stream>>>(pred, tgt, partial, cnt, out,
                                                cpb, 1.0f / (float)N);
}

// Round 4
// 35.273 us; speedup vs baseline: 1.3555x; 1.3555x over previous
//
#include <hip/hip_runtime.h>

// YOLO loss: predictions (N,7,7,30) f32, target (N,7,7,25) f32 -> scalar f32.
// S=7, B=2, C=20. Memory-bound reduction (~176 MB -> 1 float).
//
// Round 4: attack the latency bound (nothing saturated, occupancy 17%).
//  - 64-cell tiles: LDS 14080 B/block -> 11 blocks/CU x 2 waves = 22 waves/CU
//    (was 2 blocks/CU = 8 waves at 56 KB tiles).
//  - global_load_lds width=16 staging: linear LDS is exactly the
//    wave-uniform-base + lane*16 pattern; no VGPR round-trip, no ds_writes.
//  - wave role-split: wave0 = box/iou/conf terms, wave1 = class SSE term;
//    both full-width, combined only in the block sum.

#define S7 7
#define CELL_P 30
#define CELL_T 25
#define TPB 128          // 2 waves
#define CPB 64           // cells per block

__device__ __forceinline__ void gload16(const void* g, void* l)
{
    __builtin_amdgcn_global_load_lds(
        (const __attribute__((address_space(1))) unsigned int*)g,
        (__attribute__((address_space(3))) unsigned int*)l, 16, 0, 0);
}

__global__ __launch_bounds__(TPB, 6) void yolo_cell_kernel(
    const float* __restrict__ pred, const float* __restrict__ tgt,
    float* __restrict__ partial)
{
    __shared__ float sp[CPB * CELL_P];   // 7680 B, linear global layout
    __shared__ float st[CPB * CELL_T];   // 6400 B
    __shared__ float sred[2];

    const int t    = threadIdx.x;
    const int lane = t & 63;
    const int wid  = t >> 6;
    const int bid  = blockIdx.x;

    const char* P = (const char*)(pred + (size_t)bid * CPB * CELL_P); // 7680 B, 16B aligned
    const char* T = (const char*)(tgt  + (size_t)bid * CPB * CELL_T); // 6400 B, 16B aligned

    // ---- stage via global_load_lds (1 KB per op: 64 lanes x 16 B) ----
    if (wid == 0) {
        #pragma unroll
        for (int k = 0; k < 7; ++k)                       // 7168 B of pred
            gload16(P + k * 1024 + lane * 16, (char*)sp + k * 1024);
    } else {
        #pragma unroll
        for (int k = 0; k < 6; ++k)                       // 6144 B of tgt
            gload16(T + k * 1024 + lane * 16, (char*)st + k * 1024);
        if (lane < 32)                                    // pred tail 512 B
            gload16(P + 7168 + lane * 16, (char*)sp + 7168);
        if (lane < 16)                                    // tgt tail 256 B
            gload16(T + 6144 + lane * 16, (char*)st + 6144);
    }
    __syncthreads();   // compiler drains vmcnt before s_barrier

    float acc = 0.0f;

    if (wid == 0) {
        // ---- geometry wave: iou/argmax/coord/conf for cell `lane` ----
        const float* pv = sp + lane * CELL_P;
        const float* tv = st + lane * CELL_T;

        int cell = bid * CPB + lane;
        int rem  = cell % 49;
        float gx = (float)(rem % S7);   // column (axis 2)
        float gy = (float)(rem / S7);   // row    (axis 1)

        float obj = (tv[4] > 0.5f) ? 1.0f : 0.0f;

        float gcx = (gx + tv[0]) * 64.0f;
        float gcy = (gy + tv[1]) * 64.0f;
        float gw  = tv[2] * 448.0f;
        float gh  = tv[3] * 448.0f;
        float gx1 = gcx - gw * 0.5f, gy1 = gcy - gh * 0.5f;
        float gx2 = gcx + gw * 0.5f, gy2 = gcy + gh * 0.5f;
        float ga  = gw * gh;

        float iou[2], dxy[2], dwh[2], conf[2];
        #pragma unroll
        for (int b = 0; b < 2; ++b) {
            float b0 = pv[b * 5 + 0], b1 = pv[b * 5 + 1], b2 = pv[b * 5 + 2];
            float b3 = pv[b * 5 + 3], b4 = pv[b * 5 + 4];
            float pcx = (gx + b0) * 64.0f;
            float pcy = (gy + b1) * 64.0f;
            float pw  = b2 * 448.0f;
            float ph  = b3 * 448.0f;
            float px1 = pcx - pw * 0.5f, py1 = pcy - ph * 0.5f;
            float px2 = pcx + pw * 0.5f, py2 = pcy + ph * 0.5f;
            float pa  = pw * ph;

            float iw = fmaxf(fminf(px2, gx2) - fmaxf(px1, gx1), 0.0f);
            float ih = fmaxf(fminf(py2, gy2) - fmaxf(py1, gy1), 0.0f);
            float inter = iw * ih;
            iou[b] = inter / (pa + ga - inter + 1e-6f);

            float dx = b0 - tv[0], dy = b1 - tv[1];
            dxy[b] = dx * dx + dy * dy;
            float sw = sqrtf(fmaxf(b2, 0.0f)) - sqrtf(fmaxf(tv[2], 0.0f));
            float sh = sqrtf(fmaxf(b3, 0.0f)) - sqrtf(fmaxf(tv[3], 0.0f));
            dwh[b] = sw * sw + sh * sh;
            conf[b] = b4;
        }

        int best = (iou[1] > iou[0]) ? 1 : 0;   // argmax ties -> first (box 0)

        #pragma unroll
        for (int b = 0; b < 2; ++b) {
            float resp_obj = (b == best) ? obj : 0.0f;
            acc += 5.0f * resp_obj * (dxy[b] + dwh[b]);          // coord
            float d = conf[b] - iou[b];
            acc += resp_obj * d * d;                              // conf obj
            acc += 0.5f * (1.0f - resp_obj) * conf[b] * conf[b];  // conf noobj
        }
    } else {
        // ---- class wave: obj * sum((pred_cls - gt_cls)^2) for cell `lane` ----
        const float* pc = sp + lane * CELL_P + 10;
        const float* tc = st + lane * CELL_T + 5;
        float obj = (st[lane * CELL_T + 4] > 0.5f) ? 1.0f : 0.0f;

        float cls = 0.0f;
        #pragma unroll
        for (int c = 0; c < 20; ++c) {
            float d = pc[c] - tc[c];
            cls += d * d;
        }
        acc = obj * cls;
    }

    // ---- per-wave reduce, then block sum ----
    #pragma unroll
    for (int off = 32; off > 0; off >>= 1)
        acc += __shfl_down(acc, off, 64);
    if (lane == 0) sred[wid] = acc;
    __syncthreads();
    if (t == 0) partial[bid] = sred[0] + sred[1];
}

__global__ __launch_bounds__(1024) void yolo_final_kernel(
    const float* __restrict__ partial, int n, float* __restrict__ out, float invN)
{
    float s = 0.0f;
    for (int i = threadIdx.x; i < n; i += 1024)
        s += partial[i];
    #pragma unroll
    for (int off = 32; off > 0; off >>= 1)
        s += __shfl_down(s, off, 64);

    __shared__ float smem[16];
    int lane = threadIdx.x & 63;
    int wid  = threadIdx.x >> 6;
    if (lane == 0) smem[wid] = s;
    __syncthreads();
    if (threadIdx.x == 0) {
        float r = 0.0f;
        #pragma unroll
        for (int w = 0; w < 16; ++w) r += smem[w];
        out[0] = r * invN;
    }
}

extern "C" void kernel_launch(void* const* d_in, const int* in_sizes, int n_in,
                              void* d_out, int out_size, void* d_ws, size_t ws_size,
                              hipStream_t stream)
{
    const float* pred = (const float*)d_in[0];
    const float* tgt  = (const float*)d_in[1];
    float* out        = (float*)d_out;
    float* partial    = (float*)d_ws;

    int ncells = in_sizes[0] / CELL_P;   // N*S*S = 802816
    int N      = ncells / 49;
    int blocks = ncells / CPB;           // 12544, no tail

    yolo_cell_kernel<<<blocks, TPB, 0, stream>>>(pred, tgt, partial);
    yolo_final_kernel<<<1, 1024, 0, stream>>>(partial, blocks, out, 1.0f / (float)N);
}